// Round 8
// baseline (744.185 us; speedup 1.0000x reference)
//
#include <hip/hip_runtime.h>
#include <hip/hip_bf16.h>

// ---------------------------------------------------------------------------
// GCN stack: 3 graphs x 3 layers (256->256->128->64), final scalar = sum/64.
// Math: with h' = (x@W) * dis[row],
//   out[i] = relu( dis[i] * (h'[i] + sum_{e: dst=i} h'[src[e]]) + b )
// R8: CSR fill/count with 4 independent edge chains per thread (MLP on the
// atomic+store latency; fill was 22 G atomic/s vs 76 G/s fire-and-forget).
// Slots via atomicSub on cnt (degrees consumed); deg = rs[i+1]-rs[i];
// dis fused into scan1; scan2 fused into scan3. No windowing (line-granule
// writeback is structural across XCDs; windowing only added FETCH).
// ---------------------------------------------------------------------------

typedef unsigned short ushort_t;
typedef unsigned int uint_t;
typedef unsigned char uchar_t;
typedef __attribute__((ext_vector_type(8))) short v8s;   // 8 bf16
typedef __attribute__((ext_vector_type(4))) float v4f;   // MFMA accum
typedef __attribute__((ext_vector_type(2))) float v2f;

struct FP3 { const float* a; const float* b; const float* c; };
struct IP3 { const int* a; const int* b; const int* c; };

static __device__ __forceinline__ ushort_t f2bf(float f) {
    uint_t u = __float_as_uint(f);
    u += 0x7fffu + ((u >> 16) & 1u);   // RNE
    return (ushort_t)(u >> 16);
}
static __device__ __forceinline__ uint_t pack2(float a, float b) {
    return (uint_t)f2bf(a) | ((uint_t)f2bf(b) << 16);
}

// permutation within each 64-block: stored pos q holds actual col P64(q)
static __device__ __forceinline__ int P64(int q) {
    return (q & ~63) | (((q & 3) << 4) | ((q & 63) >> 2));
}

// fp8 e4m3fn encode, RNE, clamp (fallback path).
static __device__ __forceinline__ uint_t f2fp8(float f) {
    uint_t u = __float_as_uint(f);
    uint_t s = (u >> 24) & 0x80u;
    uint_t a = u & 0x7fffffffu;
    uint_t r;
    if (a >= 0x43E00000u) {
        r = 0x7Eu;
    } else if (a < 0x3C800000u) {
        r = (uint_t)(int)rintf(__uint_as_float(a) * 512.0f);
    } else {
        uint_t t = a + 0x7FFFFu + ((a >> 20) & 1u);
        r = (t >> 20) - 960u;
        if (r > 0x7Eu) r = 0x7Eu;
    }
    return s | r;
}
static __device__ __forceinline__ uint_t pack_fp8x4(float a, float b, float c, float d) {
#if __has_builtin(__builtin_amdgcn_cvt_pk_fp8_f32)
    int w = 0;
    w = __builtin_amdgcn_cvt_pk_fp8_f32(a, b, w, false);   // bytes 0,1
    w = __builtin_amdgcn_cvt_pk_fp8_f32(c, d, w, true);    // bytes 2,3
    return (uint_t)w;
#else
    return f2fp8(a) | (f2fp8(b) << 8) | (f2fp8(c) << 16) | (f2fp8(d) << 24);
#endif
}
static __device__ __forceinline__ float fp8f(uint_t b) {
    uint_t t = (b & 0x7Fu) << 20;
    float f = __uint_as_float(t) * 0x1.0p+120f;
    return __uint_as_float(__float_as_uint(f) | ((b & 0x80u) << 24));
}
static __device__ __forceinline__ float4 load_fp84(const uchar_t* p) {
    uint_t w = *(const uint_t*)p;
    float4 f;
#if __has_builtin(__builtin_amdgcn_cvt_pk_f32_fp8)
    v2f lo = __builtin_amdgcn_cvt_pk_f32_fp8((int)w, false);
    v2f hi = __builtin_amdgcn_cvt_pk_f32_fp8((int)w, true);
    f.x = lo[0]; f.y = lo[1]; f.z = hi[0]; f.w = hi[1];
#else
    f.x = fp8f(w & 0xffu); f.y = fp8f((w >> 8) & 0xffu);
    f.z = fp8f((w >> 16) & 0xffu); f.w = fp8f(w >> 24);
#endif
    return f;
}

// ---------------------------------------------------------------------------
__global__ __launch_bounds__(256) void zero1_k(int* a, int n) {
    int i = blockIdx.x * 256 + threadIdx.x;
    if (i < n) a[i] = 0;
}

// Weight transpose+convert (Wt2/Wt3 k-permuted) + permuted bias copies.
__global__ __launch_bounds__(256) void wt_all_k(
    const float* __restrict__ W1, const float* __restrict__ W2, const float* __restrict__ W3,
    const float* __restrict__ b1, const float* __restrict__ b2, const float* __restrict__ b3,
    ushort_t* __restrict__ Wt1, ushort_t* __restrict__ Wt2, ushort_t* __restrict__ Wt3,
    float* __restrict__ b1p, float* __restrict__ b2p, float* __restrict__ b3p) {
    int i = blockIdx.x * 256 + threadIdx.x;
    if (i < 65536) {
        int k = i >> 8, n = i & 255;
        Wt1[n * 256 + k] = f2bf(W1[i]);            // A of GEMM-1 (X) unpermuted
    } else if (i < 98304) {
        int j = i - 65536; int k = j >> 7, n = j & 127;   // k' in [0,256)
        Wt2[n * 256 + k] = f2bf(W2[P64(k) * 128 + n]);
    } else if (i < 106496) {
        int j = i - 98304; int k = j >> 6, n = j & 63;    // k' in [0,128)
        Wt3[n * 128 + k] = f2bf(W3[P64(k) * 64 + n]);
    } else if (i < 106752) {
        int c = i - 106496; b1p[c] = b1[P64(c)];
    } else if (i < 106880) {
        int c = i - 106752; b2p[c] = b2[P64(c)];
    } else if (i < 106944) {
        int c = i - 106880; b3p[c] = b3[P64(c)];
    }
}

// Degree count, 4 independent edges per thread (int4 loads).
__global__ __launch_bounds__(256) void count_b_k(IP3 ei, int E, int Nn, int* cnt) {
    int g = blockIdx.y;
    const int* eb = g == 0 ? ei.a : (g == 1 ? ei.b : ei.c);
    int* cg = cnt + g * Nn;
    int e0 = (blockIdx.x * 256 + threadIdx.x) * 4;
    if (e0 + 3 < E) {
        int4 d = *(const int4*)(eb + E + e0);
        atomicAdd(&cg[d.x], 1);
        atomicAdd(&cg[d.y], 1);
        atomicAdd(&cg[d.z], 1);
        atomicAdd(&cg[d.w], 1);
    } else {
        for (int e = e0; e < E; ++e) atomicAdd(&cg[eb[E + e]], 1);
    }
}

// scan1: per-chunk (4096) sums of cnt + dis = rsqrt(cnt+1).
__global__ __launch_bounds__(256) void scan1_k(const int* __restrict__ cnt,
                                               int* __restrict__ bsums,
                                               float* __restrict__ dis, int n) {
    int base = blockIdx.x * 4096 + threadIdx.x * 16;
    int s = 0;
    #pragma unroll
    for (int j = 0; j < 16; ++j) {
        int i = base + j;
        if (i < n) {
            int c = cnt[i];
            s += c;
            dis[i] = rsqrtf((float)c + 1.0f);
        }
    }
    #pragma unroll
    for (int off = 32; off > 0; off >>= 1) s += __shfl_down(s, off);
    __shared__ int wsum[4];
    int lane = threadIdx.x & 63, wid = threadIdx.x >> 6;
    if (lane == 0) wsum[wid] = s;
    __syncthreads();
    if (threadIdx.x == 0) bsums[blockIdx.x] = wsum[0] + wsum[1] + wsum[2] + wsum[3];
}

// scan3 (fused scan2): every block wave-scans the <=64 bsums, then writes its
// chunk's exclusive prefix into rs; last element also writes rs[n].
__global__ __launch_bounds__(256) void scan3_k(const int* __restrict__ cnt,
                                               const int* __restrict__ bsums, int nb,
                                               int* __restrict__ rs, int n) {
    __shared__ int boffs_s[64];
    if (threadIdx.x < 64) {
        int t = threadIdx.x;
        int v = (t < nb) ? bsums[t] : 0;
        int x = v;
        #pragma unroll
        for (int off = 1; off < 64; off <<= 1) {
            int tt = __shfl_up(x, off);
            if (t >= off) x += tt;
        }
        boffs_s[t] = x - v;
    }
    int base = blockIdx.x * 4096 + threadIdx.x * 16;
    int e[16];
    int s = 0;
    #pragma unroll
    for (int j = 0; j < 16; ++j) {
        int i = base + j;
        e[j] = (i < n) ? cnt[i] : 0;
        s += e[j];
    }
    int lane = threadIdx.x & 63, wid = threadIdx.x >> 6;
    int x = s;
    #pragma unroll
    for (int off = 1; off < 64; off <<= 1) {
        int t = __shfl_up(x, off);
        if (lane >= off) x += t;
    }
    __shared__ int wsum[4];
    if (lane == 63) wsum[wid] = x;
    __syncthreads();
    int we = 0;
    #pragma unroll
    for (int w = 0; w < 4; ++w) if (w < wid) we += wsum[w];
    int p = boffs_s[blockIdx.x] + we + (x - s);
    #pragma unroll
    for (int j = 0; j < 16; ++j) {
        int i = base + j;
        if (i < n) rs[i] = p;
        p += e[j];
        if (i == n - 1) rs[n] = p;
    }
}

// Fill: 4 independent atomic+store chains per thread. Slot = atomicSub(cnt)-1
// (consumes cnt; degrees recovered later as rs[i+1]-rs[i]).
__global__ __launch_bounds__(256) void fill_b_k(IP3 ei, int E, int Nn,
    const int* __restrict__ rs, int* __restrict__ cnt, ushort_t* __restrict__ csr) {
    int g = blockIdx.y;
    const int* eb = g == 0 ? ei.a : (g == 1 ? ei.b : ei.c);
    const int* rg = rs + g * Nn;
    int* cg = cnt + g * Nn;
    int e0 = (blockIdx.x * 256 + threadIdx.x) * 4;
    if (e0 + 3 < E) {
        int4 d = *(const int4*)(eb + E + e0);
        int4 sv = *(const int4*)(eb + e0);
        int p0 = atomicSub(&cg[d.x], 1) - 1;
        int p1 = atomicSub(&cg[d.y], 1) - 1;
        int p2 = atomicSub(&cg[d.z], 1) - 1;
        int p3 = atomicSub(&cg[d.w], 1) - 1;
        csr[rg[d.x] + p0] = (ushort_t)sv.x;
        csr[rg[d.y] + p1] = (ushort_t)sv.y;
        csr[rg[d.z] + p2] = (ushort_t)sv.z;
        csr[rg[d.w] + p3] = (ushort_t)sv.w;
    } else {
        for (int e = e0; e < E; ++e) {
            int dd = eb[E + e];
            int p = atomicSub(&cg[dd], 1) - 1;
            csr[rg[dd] + p] = (ushort_t)eb[e];
        }
    }
}

// ---------------------------------------------------------------------------
// MFMA GEMM over M = Bc*Nn rows: H8[m][c'] = fp8(D[m][P64(c')] * dis[m]).
// Direct permuted global store (no LDS round-trip, no bank conflicts).
// ---------------------------------------------------------------------------
template<int WM, int WN, bool AFP32>
__global__ __launch_bounds__(WM * WN * 64) void gemm_mfma_k(
    FP3 xp, const ushort_t* __restrict__ Ab,
    const ushort_t* __restrict__ Wt, const float* __restrict__ dis,
    uchar_t* __restrict__ out8, int M, int K, int N, int Nn)
{
    constexpr int BM = WM * 64, BN = WN * 64, NT = WM * WN * 64;
    constexpr int LDA = 40;  // ushorts; pad breaks staging-read conflicts
    __shared__ __align__(16) ushort_t As[BM * LDA];
    __shared__ __align__(16) ushort_t Bs[BN * LDA];

    const int tid  = threadIdx.x;
    const int lane = tid & 63;
    const int wave = tid >> 6;
    const int quad = lane >> 4, l16 = lane & 15;
    const int wm = wave / WN, wn = wave % WN;
    const int tile_m = blockIdx.y * BM, tile_n = blockIdx.x * BN;

    v4f acc[4][4];
    #pragma unroll
    for (int i = 0; i < 4; ++i)
        #pragma unroll
        for (int j = 0; j < 4; ++j)
            acc[i][j] = (v4f){0.f, 0.f, 0.f, 0.f};

    const float* Xrow = nullptr;
    int ar = 0, akc = 0;
    if constexpr (AFP32) {
        static_assert(BM * 4 == NT, "AFP32 staging assumes one chunk/thread");
        ar = tid >> 2; akc = (tid & 3) * 8;
        int gr = tile_m + ar;
        if (gr < M) {
            int lg = gr / Nn;
            int rl = gr - lg * Nn;
            const float* Xg = lg == 0 ? xp.a : (lg == 1 ? xp.b : xp.c);
            Xrow = Xg + (long)rl * K;
        }
    }

    for (int k0 = 0; k0 < K; k0 += 32) {
        if constexpr (AFP32) {
            uint4 w = make_uint4(0, 0, 0, 0);
            if (Xrow) {
                float4 f0 = *(const float4*)(Xrow + k0 + akc);
                float4 f1 = *(const float4*)(Xrow + k0 + akc + 4);
                w.x = pack2(f0.x, f0.y); w.y = pack2(f0.z, f0.w);
                w.z = pack2(f1.x, f1.y); w.w = pack2(f1.z, f1.w);
            }
            *(uint4*)&As[ar * LDA + akc] = w;
        } else {
            #pragma unroll
            for (int cch = tid; cch < BM * 4; cch += NT) {
                int r = cch >> 2, kc = (cch & 3) * 8;
                int gr = tile_m + r;
                uint4 w = make_uint4(0, 0, 0, 0);
                if (gr < M) w = *(const uint4*)(Ab + (long)gr * K + k0 + kc);
                *(uint4*)&As[r * LDA + kc] = w;
            }
        }
        #pragma unroll
        for (int cch = tid; cch < BN * 4; cch += NT) {
            int r = cch >> 2, kc = (cch & 3) * 8;
            uint4 w = *(const uint4*)(Wt + (long)(tile_n + r) * K + k0 + kc);
            *(uint4*)&Bs[r * LDA + kc] = w;
        }
        __syncthreads();

        v8s a[4], b[4];
        #pragma unroll
        for (int f = 0; f < 4; ++f)
            a[f] = *(const v8s*)&As[(wm * 64 + f * 16 + l16) * LDA + quad * 8];
        #pragma unroll
        for (int f = 0; f < 4; ++f)
            b[f] = *(const v8s*)&Bs[(wn * 64 + f * 16 + l16) * LDA + quad * 8];
        #pragma unroll
        for (int i = 0; i < 4; ++i)
            #pragma unroll
            for (int j = 0; j < 4; ++j)
                acc[i][j] = __builtin_amdgcn_mfma_f32_16x16x32_bf16(a[i], b[j], acc[i][j], 0, 0, 0);
        __syncthreads();
    }

    // direct permuted fp8 epilogue (C/D: col=lane&15, row=quad*4+reg)
    #pragma unroll
    for (int i = 0; i < 4; ++i) {
        #pragma unroll
        for (int r = 0; r < 4; ++r) {
            int gr = tile_m + wm * 64 + i * 16 + quad * 4 + r;
            if (gr < M) {
                float s = dis[gr];
                uint_t w = pack_fp8x4(acc[i][0][r] * s, acc[i][1][r] * s,
                                      acc[i][2][r] * s, acc[i][3][r] * s);
                *(uint_t*)(out8 + (long)gr * N + tile_n + wn * 64 + l16 * 4) = w;
            }
        }
    }
}

// OUT[i] = bf16(relu(dis[i]*(H[i] + sum_nbrs H[s]) + bp)); H fp8, cols permuted.
// deg = rs[i+1]-rs[i].
template<int F>
__global__ __launch_bounds__(256) void gather_relu_k(
    const uchar_t* __restrict__ H8, ushort_t* __restrict__ OUT,
    const int* __restrict__ rs, const ushort_t* __restrict__ csr,
    const float* __restrict__ dis, const float* __restrict__ bias, int n, int Nn)
{
    constexpr int L = F / 4;
    constexpr int NPB = 256 / L;
    int node = blockIdx.x * NPB + threadIdx.x / L;
    if (node >= n) return;
    int c = (threadIdx.x % L) * 4;
    int base = rs[node];
    int end  = rs[node + 1];
    int lg   = node / Nn;
    if constexpr (L == 64) {  // node wave-uniform: scalarize
        base = __builtin_amdgcn_readfirstlane(base);
        end  = __builtin_amdgcn_readfirstlane(end);
        lg   = __builtin_amdgcn_readfirstlane(lg);
    }
    int deg = end - base;
    long gbase = (long)lg * Nn;

    float4 acc = load_fp84(H8 + (long)node * F + c);   // self-loop
    int k = 0;
    for (; k + 3 < deg; k += 4) {
        int s0 = csr[base + k];
        int s1 = csr[base + k + 1];
        int s2 = csr[base + k + 2];
        int s3 = csr[base + k + 3];
        float4 v0 = load_fp84(H8 + (gbase + s0) * F + c);
        float4 v1 = load_fp84(H8 + (gbase + s1) * F + c);
        float4 v2 = load_fp84(H8 + (gbase + s2) * F + c);
        float4 v3 = load_fp84(H8 + (gbase + s3) * F + c);
        acc.x += (v0.x + v1.x) + (v2.x + v3.x);
        acc.y += (v0.y + v1.y) + (v2.y + v3.y);
        acc.z += (v0.z + v1.z) + (v2.z + v3.z);
        acc.w += (v0.w + v1.w) + (v2.w + v3.w);
    }
    for (; k < deg; ++k) {
        int s0 = csr[base + k];
        float4 v0 = load_fp84(H8 + (gbase + s0) * F + c);
        acc.x += v0.x; acc.y += v0.y; acc.z += v0.z; acc.w += v0.w;
    }
    float di = dis[node];
    float4 bb = *(const float4*)(bias + c);
    ushort4 o;
    o.x = f2bf(fmaxf(fmaf(di, acc.x, bb.x), 0.f));
    o.y = f2bf(fmaxf(fmaf(di, acc.y, bb.y), 0.f));
    o.z = f2bf(fmaxf(fmaf(di, acc.z, bb.z), 0.f));
    o.w = f2bf(fmaxf(fmaf(di, acc.w, bb.w), 0.f));
    *(ushort4*)(OUT + (long)node * F + c) = o;
}

// Layer-3: gather + relu + per-block partial sum (permutation-invariant).
__global__ __launch_bounds__(256) void gather_reduce_k(
    const uchar_t* __restrict__ H8,
    const int* __restrict__ rs, const ushort_t* __restrict__ csr,
    const float* __restrict__ dis, const float* __restrict__ bias,
    int n, int Nn, float* __restrict__ partial)
{
    constexpr int F = 64, L = 16, NPB = 16;
    int node = blockIdx.x * NPB + threadIdx.x / L;
    int c = (threadIdx.x % L) * 4;
    float val = 0.f;
    if (node < n) {
        int lg = node / Nn;
        long gbase = (long)lg * Nn;
        float4 acc = load_fp84(H8 + (long)node * F + c);
        int base = rs[node], deg = rs[node + 1] - base;
        int k = 0;
        for (; k + 3 < deg; k += 4) {
            int s0 = csr[base + k];
            int s1 = csr[base + k + 1];
            int s2 = csr[base + k + 2];
            int s3 = csr[base + k + 3];
            float4 v0 = load_fp84(H8 + (gbase + s0) * F + c);
            float4 v1 = load_fp84(H8 + (gbase + s1) * F + c);
            float4 v2 = load_fp84(H8 + (gbase + s2) * F + c);
            float4 v3 = load_fp84(H8 + (gbase + s3) * F + c);
            acc.x += (v0.x + v1.x) + (v2.x + v3.x);
            acc.y += (v0.y + v1.y) + (v2.y + v3.y);
            acc.z += (v0.z + v1.z) + (v2.z + v3.z);
            acc.w += (v0.w + v1.w) + (v2.w + v3.w);
        }
        for (; k < deg; ++k) {
            int s0 = csr[base + k];
            float4 v0 = load_fp84(H8 + (gbase + s0) * F + c);
            acc.x += v0.x; acc.y += v0.y; acc.z += v0.z; acc.w += v0.w;
        }
        float di = dis[node];
        float4 bb = *(const float4*)(bias + c);
        val = fmaxf(fmaf(di, acc.x, bb.x), 0.f)
            + fmaxf(fmaf(di, acc.y, bb.y), 0.f)
            + fmaxf(fmaf(di, acc.z, bb.z), 0.f)
            + fmaxf(fmaf(di, acc.w, bb.w), 0.f);
    }
    #pragma unroll
    for (int off = 32; off > 0; off >>= 1) val += __shfl_down(val, off);
    __shared__ float wsum[4];
    int lane = threadIdx.x & 63, wid = threadIdx.x >> 6;
    if (lane == 0) wsum[wid] = val;
    __syncthreads();
    if (threadIdx.x == 0)
        partial[blockIdx.x] = wsum[0] + wsum[1] + wsum[2] + wsum[3];
}

__global__ __launch_bounds__(1024) void reduce_partials_k(
    const float* __restrict__ partial, int npart, float* __restrict__ out)
{
    float s = 0.f;
    for (int i = threadIdx.x; i < npart; i += 1024) s += partial[i];
    #pragma unroll
    for (int off = 32; off > 0; off >>= 1) s += __shfl_down(s, off);
    __shared__ float wsum[16];
    int lane = threadIdx.x & 63, wid = threadIdx.x >> 6;
    if (lane == 0) wsum[wid] = s;
    __syncthreads();
    if (threadIdx.x == 0) {
        float t = 0.f;
        #pragma unroll
        for (int w = 0; w < 16; ++w) t += wsum[w];
        out[0] = t * (1.0f / 64.0f);
    }
}

extern "C" void kernel_launch(void* const* d_in, const int* in_sizes, int n_in,
                              void* d_out, int out_size, void* d_ws, size_t ws_size,
                              hipStream_t stream) {
    const float* X[3]  = {(const float*)d_in[0], (const float*)d_in[1], (const float*)d_in[2]};
    const int*   EI[3] = {(const int*)d_in[3], (const int*)d_in[4], (const int*)d_in[5]};
    const float* W1 = (const float*)d_in[6];
    const float* b1 = (const float*)d_in[7];
    const float* W2 = (const float*)d_in[8];
    const float* b2 = (const float*)d_in[9];
    const float* W3 = (const float*)d_in[10];
    const float* b3 = (const float*)d_in[11];
    float* out = (float*)d_out;

    const int Nn = in_sizes[0] / 256;   // 50000 (< 65536 for ushort csr)
    const int E  = in_sizes[3] / 2;     // 800000
    const int B  = 3;

    // ---- workspace layout (512B-aligned regions) ----
    char* base = (char*)d_ws;
    size_t off = 0;
    auto take = [&](size_t bytes) -> void* {
        void* r = base + off;
        off += (bytes + 511) & ~(size_t)511;
        return r;
    };
    float* dis = (float*)take((size_t)B * Nn * 4);
    int* cnt   = (int*)take((size_t)B * Nn * 4);
    int* rs    = (int*)take(((size_t)B * Nn + 1) * 4);
    ushort_t* csr = (ushort_t*)take((size_t)B * E * 2);
    int* bsums = (int*)take(64 * 4);
    ushort_t* Wt1 = (ushort_t*)take(256 * 256 * 2);
    ushort_t* Wt2 = (ushort_t*)take(128 * 256 * 2);
    ushort_t* Wt3 = (ushort_t*)take(64 * 128 * 2);
    float* b1p = (float*)take(256 * 4);
    float* b2p = (float*)take(128 * 4);
    float* b3p = (float*)take(64 * 4);
    float* partial = (float*)take(((size_t)B * Nn / 16 + 64) * 4);
    size_t fixed = off;
    size_t abFull = ((size_t)B * Nn * 256 * 2 + 511) & ~(size_t)511;
    size_t hbFull = ((size_t)B * Nn * 256 + 511) & ~(size_t)511;
    const bool batched = ws_size >= fixed + abFull + hbFull;
    const int Bc = batched ? 3 : 1;
    ushort_t* Ab = (ushort_t*)take((size_t)Bc * Nn * 256 * 2);
    uchar_t* Hsh = (uchar_t*)take((size_t)Bc * Nn * 256);  // fp8: [.,256]/[.,128]/[.,64]

    IP3 ei = {EI[0], EI[1], EI[2]};
    const int nb_e4 = (E + 1023) / 1024;      // 4 edges/thread
    const int nAll  = B * Nn;
    const int nb_sc = (nAll + 4095) / 4096;   // <= 64

    // ---- prep + batched CSR build (all 3 graphs) ----
    zero1_k<<<(nAll + 255) / 256, 256, 0, stream>>>(cnt, nAll);
    wt_all_k<<<(106944 + 255) / 256, 256, 0, stream>>>(
        W1, W2, W3, b1, b2, b3, Wt1, Wt2, Wt3, b1p, b2p, b3p);
    count_b_k<<<dim3(nb_e4, 3), 256, 0, stream>>>(ei, E, Nn, cnt);
    scan1_k<<<nb_sc, 256, 0, stream>>>(cnt, bsums, dis, nAll);
    scan3_k<<<nb_sc, 256, 0, stream>>>(cnt, bsums, nb_sc, rs, nAll);
    fill_b_k<<<dim3(nb_e4, 3), 256, 0, stream>>>(ei, E, Nn, rs, cnt, csr);

    // ---- layer pipeline (batched over Bc graphs per pass) ----
    const int Mp  = Bc * Nn;
    const int npb = (Mp + 15) / 16;            // gather_reduce blocks per pass
    for (int g0 = 0; g0 < B; g0 += Bc) {
        const int M = Mp;
        FP3 xp;
        if (Bc == 3) { xp.a = X[0]; xp.b = X[1]; xp.c = X[2]; }
        else         { xp.a = X[g0]; xp.b = X[g0]; xp.c = X[g0]; }
        const float* disl = dis + (size_t)g0 * Nn;
        const int*   rsl  = rs  + (size_t)g0 * Nn;

        // L1: X fp32 [M,256] @ Wt1 -> Hsh fp8 [M,256] (permuted cols)
        gemm_mfma_k<2, 4, true><<<dim3(1, (M + 127) / 128), 512, 0, stream>>>(
            xp, nullptr, Wt1, disl, Hsh, M, 256, 256, Nn);
        gather_relu_k<256><<<(M + 3) / 4, 256, 0, stream>>>(
            Hsh, Ab, rsl, csr, disl, b1p, M, Nn);

        // L2: Ab bf16 [M,256](perm) @ Wt2(perm-k) -> Hsh fp8 [M,128](perm)
        gemm_mfma_k<2, 2, false><<<dim3(1, (M + 127) / 128), 256, 0, stream>>>(
            xp, Ab, Wt2, disl, Hsh, M, 256, 128, Nn);
        gather_relu_k<128><<<(M + 7) / 8, 256, 0, stream>>>(
            Hsh, Ab, rsl, csr, disl, b2p, M, Nn);

        // L3: Ab bf16 [M,128](perm) @ Wt3(perm-k) -> Hsh fp8 [M,64](perm)
        gemm_mfma_k<2, 1, false><<<dim3(1, (M + 127) / 128), 128, 0, stream>>>(
            xp, Ab, Wt3, disl, Hsh, M, 128, 64, Nn);
        gather_reduce_k<<<npb, 256, 0, stream>>>(
            Hsh, rsl, csr, disl, b3p, M, Nn, partial + (g0 / Bc) * npb);
    }
    reduce_partials_k<<<1, 1024, 0, stream>>>(partial, (B / Bc) * npb, out);
}